// Round 12
// baseline (120.139 us; speedup 1.0000x reference)
//
#include <hip/hip_runtime.h>

#define NB 4
#define NC 16
#define NP 76800
#define NK 100
#define NITER 10
#define BW2 0.0256f
#define TPB 256
#define PT 4
#define TILEP (TPB*PT)        // 1024 points per accum block
#define NTILES (NP/TILEP)     // 75
#define KS 4                  // k-split
#define KPB (NK/KS)           // 25
// label: 1 point/thread
#define LTILEP TPB            // 256
#define LNTILES (NP/LTILEP)   // 300

// ws float-offsets
#define MEANS_OFF 0                            // [2][NB*NK][NC]
#define M2G_OFF   (MEANS_OFF + 2*NB*NK*NC)     // [NB*NK] m2 of current global means
#define GNUM_OFF  (M2G_OFF + NB*NK)            // [3][NB*NK][NC]
#define GDEN_OFF  (GNUM_OFF + 3*NB*NK*NC)      // [3][NB*NK]
#define ACNT_OFF  (GDEN_OFF + 3*NB*NK)         // int[NB*KS] active counts
#define FIN_OFF   (ACNT_OFF + NB*KS)           // int[2]: finalR, finalM
#define LBL_OFF   (FIN_OFF + 2)                // int: labels already written

__device__ __forceinline__ const float* uni(const float* p, int off) {
    return p + __builtin_amdgcn_readfirstlane(off);
}

__global__ void ms_init(const float* __restrict__ feat, const int* __restrict__ seed,
                        float* __restrict__ ws) {
    int t = blockIdx.x * blockDim.x + threadIdx.x;
    int stride = gridDim.x * blockDim.x;
    int* wsi = (int*)ws;
    for (int i = t; i < 3 * NB * NK * NC + 3 * NB * NK; i += stride)
        ws[GNUM_OFF + i] = 0.f;
    if (t < NB * KS) wsi[ACNT_OFF + t] = KPB;
    if (t < 3) wsi[FIN_OFF + t] = 0;   // finR, finM, labeled
    if (t < NB * NK) {
        int b = t / NK;
        int idx = seed[t];
        float nm[NC];
        #pragma unroll
        for (int c = 0; c < NC; ++c) nm[c] = feat[((size_t)b * NC + c) * NP + idx];
        float s = 0.f;
        #pragma unroll
        for (int c = 0; c < NC; ++c) s += nm[c] * nm[c];
        float* m = ws + MEANS_OFF + NB * NK * NC + t * NC;  // buffer 1 = means_{-1}
        #pragma unroll
        for (int c = 0; c < NC; ++c) m[c] = nm[c];
        ws[M2G_OFF + t] = s;
    }
}

// Per-k bitwise convergence skip (exact). Global-convergence early-exit; the FIRST
// converged iteration writes the labels itself (fused label), sets LBL; later
// iterations and ms_label exit on one scalar read. it==0 fast path: identity update,
// means read from global via wave-uniform scalar loads.
__global__ __launch_bounds__(TPB, 4) void ms_accum(const float* __restrict__ feat,
                                                   float* __restrict__ ws,
                                                   float* __restrict__ out,
                                                   int rIdx, int aIdx, int zIdx,
                                                   int prevM, int curM, int it) {
    __shared__ float sm[KPB][NC];
    __shared__ float sm2k[KPB];
    __shared__ float snum[KPB][NC];
    __shared__ float sden[KPB];
    __shared__ unsigned char sflag[KPB];
    __shared__ short act[KPB];
    __shared__ int nact;
    int* wsi = (int*)ws;

    const int bid = blockIdx.x;
    const int ks = bid & (KS - 1);
    const int t2 = bid >> 2;
    const int b = t2 / NTILES;
    const int tile = t2 % NTILES;
    const int tid = threadIdx.x;
    const int kbeg = ks * KPB;

    if (it >= 1) {  // global-convergence path (uniform scalar reads)
        int total = 0;
        #pragma unroll
        for (int i = 0; i < NB * KS; ++i) total += wsi[ACNT_OFF + i];
        if (total == 0) {
            if (wsi[LBL_OFF]) return;  // labels already written by an earlier iteration
            // ---- fused label: means are final & stable (published by it-1) ----
            const int finM = wsi[FIN_OFF + 1];
            const float* mPrev = ws + MEANS_OFF + (size_t)finM * NB * NK * NC
                                    + (size_t)b * NK * NC;
            if (tile == 0 && ks == 0 && tid < NK) {  // final means -> output tail
                const float4* mp4 = reinterpret_cast<const float4*>(mPrev + tid * NC);
                float4* mo4 = reinterpret_cast<float4*>(out + (size_t)NB * NP +
                                                        (size_t)b * NK * NC + tid * NC);
                mo4[0] = mp4[0]; mo4[1] = mp4[1]; mo4[2] = mp4[2]; mo4[3] = mp4[3];
            }
            if (bid == 0 && tid == 0) wsi[LBL_OFF] = 1;  // visible at next dispatch
            const int p = tile * TILEP + ks * TPB + tid;
            float fr[NC];
            #pragma unroll
            for (int c = 0; c < NC; ++c)
                fr[c] = feat[((size_t)b * NC + c) * NP + p];
            float f2 = 0.f;
            #pragma unroll
            for (int c = 0; c < NC; ++c) f2 += fr[c] * fr[c];
            float best = 3.4e38f;
            int bi = 0;
            const float* m2g = ws + M2G_OFF + b * NK;
            #pragma unroll 4
            for (int k = 0; k < NK; ++k) {
                const float* mr = uni(mPrev, k * NC);
                float mm[NC];
                #pragma unroll
                for (int c = 0; c < NC; ++c) mm[c] = mr[c];
                float m2 = *uni(m2g, k);
                float dot = 0.f;
                #pragma unroll
                for (int c = 0; c < NC; ++c) dot = fmaf(fr[c], mm[c], dot);
                float d2 = (f2 - 2.f * dot) + m2;
                if (d2 < best) { best = d2; bi = k; }
            }
            out[(size_t)b * NP + p] = (best < BW2) ? (float)(bi + 1) : 0.f;
            return;
        }
    }

    float* gnumR = ws + GNUM_OFF + (size_t)rIdx * NB * NK * NC + (size_t)b * NK * NC;
    float* gnumA = ws + GNUM_OFF + (size_t)aIdx * NB * NK * NC + (size_t)b * NK * NC;
    float* gnumZ = ws + GNUM_OFF + (size_t)zIdx * NB * NK * NC + (size_t)b * NK * NC;
    float* gdenR = ws + GDEN_OFF + rIdx * NB * NK + b * NK;
    float* gdenA = ws + GDEN_OFF + aIdx * NB * NK + b * NK;
    float* gdenZ = ws + GDEN_OFF + zIdx * NB * NK + b * NK;
    float* mPrev = ws + MEANS_OFF + (size_t)prevM * NB * NK * NC + (size_t)b * NK * NC;
    float* mCur  = ws + MEANS_OFF + (size_t)curM  * NB * NK * NC + (size_t)b * NK * NC;

    const bool isPersist = (ks == 0 && tile == 0);

    for (int i = tid; i < KPB * NC; i += TPB) (&snum[0][0])[i] = 0.f;
    if (tid < KPB) sden[tid] = 0.f;

    if (it == 0) {
        // identity update: persist copies means buffer1 -> buffer0 for it1's prologue
        if (isPersist && tid < NK) {
            const float4* mp4 = reinterpret_cast<const float4*>(mPrev + tid * NC);
            float4* mc4 = reinterpret_cast<float4*>(mCur + tid * NC);
            mc4[0] = mp4[0]; mc4[1] = mp4[1]; mc4[2] = mp4[2]; mc4[3] = mp4[3];
            if (tid == 0) { wsi[FIN_OFF] = aIdx; wsi[FIN_OFF + 1] = curM; }
        }
        if (ks == 1 && tile == 0) {
            for (int i = tid; i < NK * NC; i += TPB) gnumZ[i] = 0.f;
            if (tid < NK) gdenZ[tid] = 0.f;
        }
        __syncthreads();

        const int p0 = tile * TILEP + tid * PT;
        float fA[NC], fB[NC], fC[NC], fD[NC];
        #pragma unroll
        for (int c = 0; c < NC; ++c) {
            float4 v = *reinterpret_cast<const float4*>(feat + ((size_t)b * NC + c) * NP + p0);
            fA[c] = v.x; fB[c] = v.y; fC[c] = v.z; fD[c] = v.w;
        }
        float f2A = 0.f, f2B = 0.f, f2C = 0.f, f2D = 0.f;
        #pragma unroll
        for (int c = 0; c < NC; ++c) f2A += fA[c] * fA[c];
        #pragma unroll
        for (int c = 0; c < NC; ++c) f2B += fB[c] * fB[c];
        #pragma unroll
        for (int c = 0; c < NC; ++c) f2C += fC[c] * fC[c];
        #pragma unroll
        for (int c = 0; c < NC; ++c) f2D += fD[c] * fD[c];

        const float* m2g = ws + M2G_OFF + b * NK;
        #pragma unroll 2
        for (int k = kbeg; k < kbeg + KPB; ++k) {
            const float* mr = uni(mPrev, k * NC);
            float mm[NC];
            #pragma unroll
            for (int c = 0; c < NC; ++c) mm[c] = mr[c];
            float m2 = *uni(m2g, k);
            float dA = 0.f, dB = 0.f, dC = 0.f, dD = 0.f;
            #pragma unroll
            for (int c = 0; c < NC; ++c) {
                float mc = mm[c];
                dA = fmaf(fA[c], mc, dA);
                dB = fmaf(fB[c], mc, dB);
                dC = fmaf(fC[c], mc, dC);
                dD = fmaf(fD[c], mc, dD);
            }
            float d2A = (f2A - 2.f * dA) + m2;
            float d2B = (f2B - 2.f * dB) + m2;
            float d2C = (f2C - 2.f * dC) + m2;
            float d2D = (f2D - 2.f * dD) + m2;
            bool hA = d2A < BW2, hB = d2B < BW2, hC = d2C < BW2, hD = d2D < BW2;
            if (__any(hA | hB | hC | hD)) {
                int loc = k - kbeg;
                if (hA) {
                    #pragma unroll
                    for (int c = 0; c < NC; ++c) atomicAdd(&snum[loc][c], fA[c]);
                    atomicAdd(&sden[loc], 1.f);
                }
                if (hB) {
                    #pragma unroll
                    for (int c = 0; c < NC; ++c) atomicAdd(&snum[loc][c], fB[c]);
                    atomicAdd(&sden[loc], 1.f);
                }
                if (hC) {
                    #pragma unroll
                    for (int c = 0; c < NC; ++c) atomicAdd(&snum[loc][c], fC[c]);
                    atomicAdd(&sden[loc], 1.f);
                }
                if (hD) {
                    #pragma unroll
                    for (int c = 0; c < NC; ++c) atomicAdd(&snum[loc][c], fD[c]);
                    atomicAdd(&sden[loc], 1.f);
                }
            }
        }

        __syncthreads();
        for (int i = tid; i < KPB * NC; i += TPB) {
            float v = (&snum[0][0])[i];
            if (v != 0.f) atomicAdd(&gnumA[kbeg * NC + i], v);
        }
        if (tid < KPB) {
            float v = sden[tid];
            if (v != 0.f) atomicAdd(&gdenA[kbeg + tid], v);
        }
        return;
    }

    // ---- it >= 1 (not globally converged): trimmed prologue + flags + publish ----
    const int nloc = isPersist ? NK : KPB;
    if (tid < nloc) {
        const int k = isPersist ? tid : (kbeg + tid);
        float den = gdenR[k];
        const float4* gn4 = reinterpret_cast<const float4*>(gnumR + k * NC);
        const float4* mp4 = reinterpret_cast<const float4*>(mPrev + k * NC);
        float4 g0 = gn4[0], g1 = gn4[1], g2 = gn4[2], g3 = gn4[3];
        float4 o0 = mp4[0], o1 = mp4[1], o2 = mp4[2], o3 = mp4[3];
        float gg[NC] = {g0.x,g0.y,g0.z,g0.w, g1.x,g1.y,g1.z,g1.w,
                        g2.x,g2.y,g2.z,g2.w, g3.x,g3.y,g3.z,g3.w};
        float oo[NC] = {o0.x,o0.y,o0.z,o0.w, o1.x,o1.y,o1.z,o1.w,
                        o2.x,o2.y,o2.z,o2.w, o3.x,o3.y,o3.z,o3.w};
        float inv = fmaxf(den, 1.f);
        bool pos = den > 0.f;
        float nm[NC];
        #pragma unroll
        for (int c = 0; c < NC; ++c) nm[c] = pos ? (gg[c] / inv) : oo[c];
        bool same = true;
        #pragma unroll
        for (int c = 0; c < NC; ++c)
            same = same && (__float_as_uint(nm[c]) == __float_as_uint(oo[c]));
        float s = 0.f;
        #pragma unroll
        for (int c = 0; c < NC; ++c) s += nm[c] * nm[c];
        const int loc = k - kbeg;
        if (loc >= 0 && loc < KPB) {
            #pragma unroll
            for (int c = 0; c < NC; ++c) sm[loc][c] = nm[c];
            sm2k[loc] = s;
            sflag[loc] = same ? (unsigned char)1 : (unsigned char)0;
        }
        if (isPersist) {
            float4* mc4 = reinterpret_cast<float4*>(mCur + k * NC);
            mc4[0] = make_float4(nm[0], nm[1], nm[2], nm[3]);
            mc4[1] = make_float4(nm[4], nm[5], nm[6], nm[7]);
            mc4[2] = make_float4(nm[8], nm[9], nm[10], nm[11]);
            mc4[3] = make_float4(nm[12], nm[13], nm[14], nm[15]);
            ws[M2G_OFF + b * NK + k] = s;
            if (same) {  // converged k: sums bitwise equal -> copy
                float4* ga4 = reinterpret_cast<float4*>(gnumA + k * NC);
                ga4[0] = g0; ga4[1] = g1; ga4[2] = g2; ga4[3] = g3;
                gdenA[k] = den;
            }
            if (tid == 0) { wsi[FIN_OFF] = aIdx; wsi[FIN_OFF + 1] = curM; }
        }
    }
    if (ks == 1 && tile == 0) {
        for (int i = tid; i < NK * NC; i += TPB) gnumZ[i] = 0.f;
        if (tid < NK) gdenZ[tid] = 0.f;
    }
    __syncthreads();

    if (tid == 0) {
        int n = 0;
        for (int loc = 0; loc < KPB; ++loc)
            if (!sflag[loc]) act[n++] = (short)loc;
        nact = n;
        if (tile == 0) wsi[ACNT_OFF + b * KS + ks] = n;
    }
    __syncthreads();
    if (nact == 0) return;

    const int p0 = tile * TILEP + tid * PT;
    float fA[NC], fB[NC], fC[NC], fD[NC];
    #pragma unroll
    for (int c = 0; c < NC; ++c) {
        float4 v = *reinterpret_cast<const float4*>(feat + ((size_t)b * NC + c) * NP + p0);
        fA[c] = v.x; fB[c] = v.y; fC[c] = v.z; fD[c] = v.w;
    }
    float f2A = 0.f, f2B = 0.f, f2C = 0.f, f2D = 0.f;
    #pragma unroll
    for (int c = 0; c < NC; ++c) f2A += fA[c] * fA[c];
    #pragma unroll
    for (int c = 0; c < NC; ++c) f2B += fB[c] * fB[c];
    #pragma unroll
    for (int c = 0; c < NC; ++c) f2C += fC[c] * fC[c];
    #pragma unroll
    for (int c = 0; c < NC; ++c) f2D += fD[c] * fD[c];

    const float4* smv = reinterpret_cast<const float4*>(&sm[0][0]);
    #pragma unroll 2
    for (int ii = 0; ii < nact; ++ii) {
        const int loc = act[ii];
        float4 m0 = smv[loc * 4 + 0], m1 = smv[loc * 4 + 1];
        float4 m2v = smv[loc * 4 + 2], m3 = smv[loc * 4 + 3];
        float mm[NC] = {m0.x,m0.y,m0.z,m0.w, m1.x,m1.y,m1.z,m1.w,
                        m2v.x,m2v.y,m2v.z,m2v.w, m3.x,m3.y,m3.z,m3.w};
        float m2 = sm2k[loc];
        float dA = 0.f, dB = 0.f, dC = 0.f, dD = 0.f;
        #pragma unroll
        for (int c = 0; c < NC; ++c) {
            float mc = mm[c];
            dA = fmaf(fA[c], mc, dA);
            dB = fmaf(fB[c], mc, dB);
            dC = fmaf(fC[c], mc, dC);
            dD = fmaf(fD[c], mc, dD);
        }
        float d2A = (f2A - 2.f * dA) + m2;
        float d2B = (f2B - 2.f * dB) + m2;
        float d2C = (f2C - 2.f * dC) + m2;
        float d2D = (f2D - 2.f * dD) + m2;
        bool hA = d2A < BW2, hB = d2B < BW2, hC = d2C < BW2, hD = d2D < BW2;
        if (__any(hA | hB | hC | hD)) {
            if (hA) {
                #pragma unroll
                for (int c = 0; c < NC; ++c) atomicAdd(&snum[loc][c], fA[c]);
                atomicAdd(&sden[loc], 1.f);
            }
            if (hB) {
                #pragma unroll
                for (int c = 0; c < NC; ++c) atomicAdd(&snum[loc][c], fB[c]);
                atomicAdd(&sden[loc], 1.f);
            }
            if (hC) {
                #pragma unroll
                for (int c = 0; c < NC; ++c) atomicAdd(&snum[loc][c], fC[c]);
                atomicAdd(&sden[loc], 1.f);
            }
            if (hD) {
                #pragma unroll
                for (int c = 0; c < NC; ++c) atomicAdd(&snum[loc][c], fD[c]);
                atomicAdd(&sden[loc], 1.f);
            }
        }
    }

    __syncthreads();
    for (int i = tid; i < KPB * NC; i += TPB) {
        float v = (&snum[0][0])[i];
        if (v != 0.f) atomicAdd(&gnumA[kbeg * NC + i], v);
    }
    if (tid < KPB) {
        float v = sden[tid];
        if (v != 0.f) atomicAdd(&gdenA[kbeg + tid], v);
    }
}

__global__ __launch_bounds__(TPB, 4) void ms_label(const float* __restrict__ feat,
                                                   float* __restrict__ ws,
                                                   float* __restrict__ out) {
    __shared__ float sm[NK][NC];
    __shared__ float sm2[NK];
    int* wsi = (int*)ws;
    if (wsi[LBL_OFF]) return;   // labels already written by a fused-label iteration

    int total = 0;
    #pragma unroll
    for (int i = 0; i < NB * KS; ++i) total += wsi[ACNT_OFF + i];
    const int finR = wsi[FIN_OFF], finM = wsi[FIN_OFF + 1];

    const int b = blockIdx.x / LNTILES;
    const int tile = blockIdx.x % LNTILES;
    const int tid = threadIdx.x;
    float* mPrev = ws + MEANS_OFF + (size_t)finM * NB * NK * NC + (size_t)b * NK * NC;

    const int p = tile * LTILEP + tid;
    float fr[NC];
    #pragma unroll
    for (int c = 0; c < NC; ++c)
        fr[c] = feat[((size_t)b * NC + c) * NP + p];
    float f2 = 0.f;
    #pragma unroll
    for (int c = 0; c < NC; ++c) f2 += fr[c] * fr[c];

    float best = 3.4e38f;
    int bi = 0;

    if (total == 0) {
        // converged but not yet labeled (convergence first observed after it9)
        if (tile == 0 && tid < NK) {
            const float4* mp4 = reinterpret_cast<const float4*>(mPrev + tid * NC);
            float4* mo4 = reinterpret_cast<float4*>(out + (size_t)NB * NP +
                                                    (size_t)b * NK * NC + tid * NC);
            mo4[0] = mp4[0]; mo4[1] = mp4[1]; mo4[2] = mp4[2]; mo4[3] = mp4[3];
        }
        const float* m2g = ws + M2G_OFF + b * NK;
        #pragma unroll 4
        for (int k = 0; k < NK; ++k) {
            const float* mr = uni(mPrev, k * NC);
            float mm[NC];
            #pragma unroll
            for (int c = 0; c < NC; ++c) mm[c] = mr[c];
            float m2 = *uni(m2g, k);
            float dot = 0.f;
            #pragma unroll
            for (int c = 0; c < NC; ++c) dot = fmaf(fr[c], mm[c], dot);
            float d2 = (f2 - 2.f * dot) + m2;
            if (d2 < best) { best = d2; bi = k; }
        }
    } else {
        float* gnumR = ws + GNUM_OFF + (size_t)finR * NB * NK * NC + (size_t)b * NK * NC;
        float* gdenR = ws + GDEN_OFF + finR * NB * NK + b * NK;
        if (tid < NK) {
            const int k = tid;
            float den = gdenR[k];
            const float4* gn4 = reinterpret_cast<const float4*>(gnumR + k * NC);
            const float4* mp4 = reinterpret_cast<const float4*>(mPrev + k * NC);
            float4 g0 = gn4[0], g1 = gn4[1], g2 = gn4[2], g3 = gn4[3];
            float4 o0 = mp4[0], o1 = mp4[1], o2 = mp4[2], o3 = mp4[3];
            float gg[NC] = {g0.x,g0.y,g0.z,g0.w, g1.x,g1.y,g1.z,g1.w,
                            g2.x,g2.y,g2.z,g2.w, g3.x,g3.y,g3.z,g3.w};
            float oo[NC] = {o0.x,o0.y,o0.z,o0.w, o1.x,o1.y,o1.z,o1.w,
                            o2.x,o2.y,o2.z,o2.w, o3.x,o3.y,o3.z,o3.w};
            float inv = fmaxf(den, 1.f);
            bool pos = den > 0.f;
            float nm[NC];
            #pragma unroll
            for (int c = 0; c < NC; ++c) nm[c] = pos ? (gg[c] / inv) : oo[c];
            #pragma unroll
            for (int c = 0; c < NC; ++c) sm[k][c] = nm[c];
            float s = 0.f;
            #pragma unroll
            for (int c = 0; c < NC; ++c) s += nm[c] * nm[c];
            sm2[k] = s;
            if (tile == 0) {
                float* mo = out + (size_t)NB * NP + (size_t)b * NK * NC + k * NC;
                float4* mo4 = reinterpret_cast<float4*>(mo);
                mo4[0] = make_float4(nm[0], nm[1], nm[2], nm[3]);
                mo4[1] = make_float4(nm[4], nm[5], nm[6], nm[7]);
                mo4[2] = make_float4(nm[8], nm[9], nm[10], nm[11]);
                mo4[3] = make_float4(nm[12], nm[13], nm[14], nm[15]);
            }
        }
        __syncthreads();
        const float4* smv = reinterpret_cast<const float4*>(&sm[0][0]);
        #pragma unroll 4
        for (int k = 0; k < NK; ++k) {
            float4 m0 = smv[k * 4 + 0], m1 = smv[k * 4 + 1];
            float4 m2v = smv[k * 4 + 2], m3 = smv[k * 4 + 3];
            float mm[NC] = {m0.x,m0.y,m0.z,m0.w, m1.x,m1.y,m1.z,m1.w,
                            m2v.x,m2v.y,m2v.z,m2v.w, m3.x,m3.y,m3.z,m3.w};
            float m2 = sm2[k];
            float dot = 0.f;
            #pragma unroll
            for (int c = 0; c < NC; ++c) dot = fmaf(fr[c], mm[c], dot);
            float d2 = (f2 - 2.f * dot) + m2;
            if (d2 < best) { best = d2; bi = k; }
        }
    }

    out[(size_t)b * NP + p] = (best < BW2) ? (float)(bi + 1) : 0.f;
}

extern "C" void kernel_launch(void* const* d_in, const int* in_sizes, int n_in,
                              void* d_out, int out_size, void* d_ws, size_t ws_size,
                              hipStream_t stream) {
    const float* feat = (const float*)d_in[0];
    const int* seed = (const int*)d_in[1];
    float* out = (float*)d_out;
    float* ws = (float*)d_ws;

    ms_init<<<84, 256, 0, stream>>>(feat, seed, ws);
    for (int i = 0; i < NITER; ++i) {
        ms_accum<<<NB * NTILES * KS, TPB, 0, stream>>>(
            feat, ws, out, (i + 2) % 3, i % 3, (i + 1) % 3, (i + 1) & 1, i & 1, i);
    }
    ms_label<<<NB * LNTILES, TPB, 0, stream>>>(feat, ws, out);
}

// Round 13
// 80.487 us; speedup vs baseline: 1.4927x; 1.4927x over previous
//
#include <hip/hip_runtime.h>

#define NB 4
#define NC 16
#define NP 76800
#define NK 100
#define NITER 10
#define BW2 0.0256f
#define TPB 256
#define PT 4
#define TILEP (TPB*PT)        // 1024 points per accum block
#define NTILES (NP/TILEP)     // 75
#define KS 4                  // k-split
#define KPB (NK/KS)           // 25
// label: 2 points/thread, strided by TPB (both coalesced)
#define LPT 2
#define LTILEP (TPB*LPT)      // 512
#define LNT (NP/LTILEP)       // 150

// ws float-offsets
#define MEANS_OFF 0                            // [2][NB*NK][NC]
#define M2G_OFF   (MEANS_OFF + 2*NB*NK*NC)     // [NB*NK] m2 of current global means
#define GNUM_OFF  (M2G_OFF + NB*NK)            // [3][NB*NK][NC]
#define GDEN_OFF  (GNUM_OFF + 3*NB*NK*NC)      // [3][NB*NK]
#define ACNT_OFF  (GDEN_OFF + 3*NB*NK)         // int[NB*KS] active counts
#define FIN_OFF   (ACNT_OFF + NB*KS)           // int[2]: finalR, finalM

__device__ __forceinline__ const float* uni(const float* p, int off) {
    return p + __builtin_amdgcn_readfirstlane(off);
}

__global__ void ms_init(const float* __restrict__ feat, const int* __restrict__ seed,
                        float* __restrict__ ws) {
    int t = blockIdx.x * blockDim.x + threadIdx.x;
    int stride = gridDim.x * blockDim.x;
    int* wsi = (int*)ws;
    for (int i = t; i < 3 * NB * NK * NC + 3 * NB * NK; i += stride)
        ws[GNUM_OFF + i] = 0.f;
    if (t < NB * KS) wsi[ACNT_OFF + t] = KPB;
    if (t < 2) wsi[FIN_OFF + t] = 0;
    if (t < NB * NK) {
        int b = t / NK;
        int idx = seed[t];
        float nm[NC];
        #pragma unroll
        for (int c = 0; c < NC; ++c) nm[c] = feat[((size_t)b * NC + c) * NP + idx];
        float s = 0.f;
        #pragma unroll
        for (int c = 0; c < NC; ++c) s += nm[c] * nm[c];
        float* m = ws + MEANS_OFF + NB * NK * NC + t * NC;  // buffer 1 = means_{-1}
        #pragma unroll
        for (int c = 0; c < NC; ++c) m[c] = nm[c];
        ws[M2G_OFF + t] = s;
    }
}

// Per-k bitwise convergence skip (exact; sums are pure functions of the mean).
// Global-convergence early-exit: once Sum(acnt)==0, all remaining iterations are
// bitwise identities -> exit without touching buffers; fin=(finalR,finalM) tells
// label which gnum/means buffers are live. it==0 fast path: update is identity
// (dens all 0), means already in global -> s_load hot loop, no LDS means.
__global__ __launch_bounds__(TPB, 4) void ms_accum(const float* __restrict__ feat,
                                                   float* __restrict__ ws,
                                                   int rIdx, int aIdx, int zIdx,
                                                   int prevM, int curM, int it) {
    __shared__ float sm[KPB][NC];
    __shared__ float sm2k[KPB];
    __shared__ float snum[KPB][NC];
    __shared__ float sden[KPB];
    __shared__ unsigned char sflag[KPB];
    __shared__ short act[KPB];
    __shared__ int nact;
    int* wsi = (int*)ws;

    if (it >= 1) {  // global-convergence early exit (uniform scalar reads)
        int total = 0;
        #pragma unroll
        for (int i = 0; i < NB * KS; ++i) total += wsi[ACNT_OFF + i];
        if (total == 0) return;
    }

    const int bid = blockIdx.x;
    const int ks = bid & (KS - 1);
    const int t2 = bid >> 2;
    const int b = t2 / NTILES;
    const int tile = t2 % NTILES;
    const int tid = threadIdx.x;
    const int kbeg = ks * KPB;

    float* gnumR = ws + GNUM_OFF + (size_t)rIdx * NB * NK * NC + (size_t)b * NK * NC;
    float* gnumA = ws + GNUM_OFF + (size_t)aIdx * NB * NK * NC + (size_t)b * NK * NC;
    float* gnumZ = ws + GNUM_OFF + (size_t)zIdx * NB * NK * NC + (size_t)b * NK * NC;
    float* gdenR = ws + GDEN_OFF + rIdx * NB * NK + b * NK;
    float* gdenA = ws + GDEN_OFF + aIdx * NB * NK + b * NK;
    float* gdenZ = ws + GDEN_OFF + zIdx * NB * NK + b * NK;
    float* mPrev = ws + MEANS_OFF + (size_t)prevM * NB * NK * NC + (size_t)b * NK * NC;
    float* mCur  = ws + MEANS_OFF + (size_t)curM  * NB * NK * NC + (size_t)b * NK * NC;

    const bool isPersist = (ks == 0 && tile == 0);

    for (int i = tid; i < KPB * NC; i += TPB) (&snum[0][0])[i] = 0.f;
    if (tid < KPB) sden[tid] = 0.f;

    if (it == 0) {
        // identity update: persist copies means buffer1 -> buffer0 for it1's prologue
        if (isPersist && tid < NK) {
            const float4* mp4 = reinterpret_cast<const float4*>(mPrev + tid * NC);
            float4* mc4 = reinterpret_cast<float4*>(mCur + tid * NC);
            mc4[0] = mp4[0]; mc4[1] = mp4[1]; mc4[2] = mp4[2]; mc4[3] = mp4[3];
            if (tid == 0) { wsi[FIN_OFF] = aIdx; wsi[FIN_OFF + 1] = curM; }
        }
        if (ks == 1 && tile == 0) {
            for (int i = tid; i < NK * NC; i += TPB) gnumZ[i] = 0.f;
            if (tid < NK) gdenZ[tid] = 0.f;
        }
        __syncthreads();

        const int p0 = tile * TILEP + tid * PT;
        float fA[NC], fB[NC], fC[NC], fD[NC];
        #pragma unroll
        for (int c = 0; c < NC; ++c) {
            float4 v = *reinterpret_cast<const float4*>(feat + ((size_t)b * NC + c) * NP + p0);
            fA[c] = v.x; fB[c] = v.y; fC[c] = v.z; fD[c] = v.w;
        }
        float f2A = 0.f, f2B = 0.f, f2C = 0.f, f2D = 0.f;
        #pragma unroll
        for (int c = 0; c < NC; ++c) f2A += fA[c] * fA[c];
        #pragma unroll
        for (int c = 0; c < NC; ++c) f2B += fB[c] * fB[c];
        #pragma unroll
        for (int c = 0; c < NC; ++c) f2C += fC[c] * fC[c];
        #pragma unroll
        for (int c = 0; c < NC; ++c) f2D += fD[c] * fD[c];

        const float* m2g = ws + M2G_OFF + b * NK;
        #pragma unroll 2
        for (int k = kbeg; k < kbeg + KPB; ++k) {
            const float* mr = uni(mPrev, k * NC);
            float mm[NC];
            #pragma unroll
            for (int c = 0; c < NC; ++c) mm[c] = mr[c];
            float m2 = *uni(m2g, k);
            float dA = 0.f, dB = 0.f, dC = 0.f, dD = 0.f;
            #pragma unroll
            for (int c = 0; c < NC; ++c) {
                float mc = mm[c];
                dA = fmaf(fA[c], mc, dA);
                dB = fmaf(fB[c], mc, dB);
                dC = fmaf(fC[c], mc, dC);
                dD = fmaf(fD[c], mc, dD);
            }
            float d2A = (f2A - 2.f * dA) + m2;
            float d2B = (f2B - 2.f * dB) + m2;
            float d2C = (f2C - 2.f * dC) + m2;
            float d2D = (f2D - 2.f * dD) + m2;
            bool hA = d2A < BW2, hB = d2B < BW2, hC = d2C < BW2, hD = d2D < BW2;
            if (__any(hA | hB | hC | hD)) {
                int loc = k - kbeg;
                if (hA) {
                    #pragma unroll
                    for (int c = 0; c < NC; ++c) atomicAdd(&snum[loc][c], fA[c]);
                    atomicAdd(&sden[loc], 1.f);
                }
                if (hB) {
                    #pragma unroll
                    for (int c = 0; c < NC; ++c) atomicAdd(&snum[loc][c], fB[c]);
                    atomicAdd(&sden[loc], 1.f);
                }
                if (hC) {
                    #pragma unroll
                    for (int c = 0; c < NC; ++c) atomicAdd(&snum[loc][c], fC[c]);
                    atomicAdd(&sden[loc], 1.f);
                }
                if (hD) {
                    #pragma unroll
                    for (int c = 0; c < NC; ++c) atomicAdd(&snum[loc][c], fD[c]);
                    atomicAdd(&sden[loc], 1.f);
                }
            }
        }

        __syncthreads();
        for (int i = tid; i < KPB * NC; i += TPB) {
            float v = (&snum[0][0])[i];
            if (v != 0.f) atomicAdd(&gnumA[kbeg * NC + i], v);
        }
        if (tid < KPB) {
            float v = sden[tid];
            if (v != 0.f) atomicAdd(&gdenA[kbeg + tid], v);
        }
        return;
    }

    // ---- it >= 1: trimmed prologue + flags + persist/copy + acnt publish ----
    const int nloc = isPersist ? NK : KPB;
    if (tid < nloc) {
        const int k = isPersist ? tid : (kbeg + tid);
        float den = gdenR[k];
        const float4* gn4 = reinterpret_cast<const float4*>(gnumR + k * NC);
        const float4* mp4 = reinterpret_cast<const float4*>(mPrev + k * NC);
        float4 g0 = gn4[0], g1 = gn4[1], g2 = gn4[2], g3 = gn4[3];
        float4 o0 = mp4[0], o1 = mp4[1], o2 = mp4[2], o3 = mp4[3];
        float gg[NC] = {g0.x,g0.y,g0.z,g0.w, g1.x,g1.y,g1.z,g1.w,
                        g2.x,g2.y,g2.z,g2.w, g3.x,g3.y,g3.z,g3.w};
        float oo[NC] = {o0.x,o0.y,o0.z,o0.w, o1.x,o1.y,o1.z,o1.w,
                        o2.x,o2.y,o2.z,o2.w, o3.x,o3.y,o3.z,o3.w};
        float inv = fmaxf(den, 1.f);
        bool pos = den > 0.f;
        float nm[NC];
        #pragma unroll
        for (int c = 0; c < NC; ++c) nm[c] = pos ? (gg[c] / inv) : oo[c];
        bool same = true;
        #pragma unroll
        for (int c = 0; c < NC; ++c)
            same = same && (__float_as_uint(nm[c]) == __float_as_uint(oo[c]));
        float s = 0.f;
        #pragma unroll
        for (int c = 0; c < NC; ++c) s += nm[c] * nm[c];
        const int loc = k - kbeg;
        if (loc >= 0 && loc < KPB) {
            #pragma unroll
            for (int c = 0; c < NC; ++c) sm[loc][c] = nm[c];
            sm2k[loc] = s;
            sflag[loc] = same ? (unsigned char)1 : (unsigned char)0;
        }
        if (isPersist) {
            float4* mc4 = reinterpret_cast<float4*>(mCur + k * NC);
            mc4[0] = make_float4(nm[0], nm[1], nm[2], nm[3]);
            mc4[1] = make_float4(nm[4], nm[5], nm[6], nm[7]);
            mc4[2] = make_float4(nm[8], nm[9], nm[10], nm[11]);
            mc4[3] = make_float4(nm[12], nm[13], nm[14], nm[15]);
            ws[M2G_OFF + b * NK + k] = s;
            if (same) {  // converged k: sums bitwise equal -> copy
                float4* ga4 = reinterpret_cast<float4*>(gnumA + k * NC);
                ga4[0] = g0; ga4[1] = g1; ga4[2] = g2; ga4[3] = g3;
                gdenA[k] = den;
            }
            if (tid == 0) { wsi[FIN_OFF] = aIdx; wsi[FIN_OFF + 1] = curM; }
        }
    }
    if (ks == 1 && tile == 0) {
        for (int i = tid; i < NK * NC; i += TPB) gnumZ[i] = 0.f;
        if (tid < NK) gdenZ[tid] = 0.f;
    }
    __syncthreads();

    if (tid == 0) {
        int n = 0;
        for (int loc = 0; loc < KPB; ++loc)
            if (!sflag[loc]) act[n++] = (short)loc;
        nact = n;
        if (tile == 0) wsi[ACNT_OFF + b * KS + ks] = n;
    }
    __syncthreads();
    if (nact == 0) return;

    const int p0 = tile * TILEP + tid * PT;
    float fA[NC], fB[NC], fC[NC], fD[NC];
    #pragma unroll
    for (int c = 0; c < NC; ++c) {
        float4 v = *reinterpret_cast<const float4*>(feat + ((size_t)b * NC + c) * NP + p0);
        fA[c] = v.x; fB[c] = v.y; fC[c] = v.z; fD[c] = v.w;
    }
    float f2A = 0.f, f2B = 0.f, f2C = 0.f, f2D = 0.f;
    #pragma unroll
    for (int c = 0; c < NC; ++c) f2A += fA[c] * fA[c];
    #pragma unroll
    for (int c = 0; c < NC; ++c) f2B += fB[c] * fB[c];
    #pragma unroll
    for (int c = 0; c < NC; ++c) f2C += fC[c] * fC[c];
    #pragma unroll
    for (int c = 0; c < NC; ++c) f2D += fD[c] * fD[c];

    const float4* smv = reinterpret_cast<const float4*>(&sm[0][0]);
    #pragma unroll 2
    for (int ii = 0; ii < nact; ++ii) {
        const int loc = act[ii];
        float4 m0 = smv[loc * 4 + 0], m1 = smv[loc * 4 + 1];
        float4 m2v = smv[loc * 4 + 2], m3 = smv[loc * 4 + 3];
        float mm[NC] = {m0.x,m0.y,m0.z,m0.w, m1.x,m1.y,m1.z,m1.w,
                        m2v.x,m2v.y,m2v.z,m2v.w, m3.x,m3.y,m3.z,m3.w};
        float m2 = sm2k[loc];
        float dA = 0.f, dB = 0.f, dC = 0.f, dD = 0.f;
        #pragma unroll
        for (int c = 0; c < NC; ++c) {
            float mc = mm[c];
            dA = fmaf(fA[c], mc, dA);
            dB = fmaf(fB[c], mc, dB);
            dC = fmaf(fC[c], mc, dC);
            dD = fmaf(fD[c], mc, dD);
        }
        float d2A = (f2A - 2.f * dA) + m2;
        float d2B = (f2B - 2.f * dB) + m2;
        float d2C = (f2C - 2.f * dC) + m2;
        float d2D = (f2D - 2.f * dD) + m2;
        bool hA = d2A < BW2, hB = d2B < BW2, hC = d2C < BW2, hD = d2D < BW2;
        if (__any(hA | hB | hC | hD)) {
            if (hA) {
                #pragma unroll
                for (int c = 0; c < NC; ++c) atomicAdd(&snum[loc][c], fA[c]);
                atomicAdd(&sden[loc], 1.f);
            }
            if (hB) {
                #pragma unroll
                for (int c = 0; c < NC; ++c) atomicAdd(&snum[loc][c], fB[c]);
                atomicAdd(&sden[loc], 1.f);
            }
            if (hC) {
                #pragma unroll
                for (int c = 0; c < NC; ++c) atomicAdd(&snum[loc][c], fC[c]);
                atomicAdd(&sden[loc], 1.f);
            }
            if (hD) {
                #pragma unroll
                for (int c = 0; c < NC; ++c) atomicAdd(&snum[loc][c], fD[c]);
                atomicAdd(&sden[loc], 1.f);
            }
        }
    }

    __syncthreads();
    for (int i = tid; i < KPB * NC; i += TPB) {
        float v = (&snum[0][0])[i];
        if (v != 0.f) atomicAdd(&gnumA[kbeg * NC + i], v);
    }
    if (tid < KPB) {
        float v = sden[tid];
        if (v != 0.f) atomicAdd(&gdenA[kbeg + tid], v);
    }
}

// Label: LDS-staged means + 2 points/thread (strided by TPB) + unroll-2 over k
// -> 4 independent FMA chains amortize each LDS mean broadcast.
__global__ __launch_bounds__(TPB, 4) void ms_label(const float* __restrict__ feat,
                                                   float* __restrict__ ws,
                                                   float* __restrict__ out) {
    __shared__ float sm[NK][NC];
    __shared__ float sm2[NK];
    int* wsi = (int*)ws;
    int total = 0;
    #pragma unroll
    for (int i = 0; i < NB * KS; ++i) total += wsi[ACNT_OFF + i];
    const int finR = wsi[FIN_OFF], finM = wsi[FIN_OFF + 1];

    const int b = blockIdx.x / LNT;
    const int tile = blockIdx.x % LNT;
    const int tid = threadIdx.x;
    float* mPrev = ws + MEANS_OFF + (size_t)finM * NB * NK * NC + (size_t)b * NK * NC;

    if (total == 0) {
        // converged: final means == mPrev bitwise; m2g valid. Stage to LDS (copies).
        if (tid < NK) {
            const float4* mp4 = reinterpret_cast<const float4*>(mPrev + tid * NC);
            float4* s4 = reinterpret_cast<float4*>(&sm[tid][0]);
            float4 a = mp4[0], q = mp4[1], r = mp4[2], s = mp4[3];
            s4[0] = a; s4[1] = q; s4[2] = r; s4[3] = s;
            sm2[tid] = ws[M2G_OFF + b * NK + tid];
            if (tile == 0) {  // final means -> output tail (bitwise copy)
                float4* mo4 = reinterpret_cast<float4*>(out + (size_t)NB * NP +
                                                        (size_t)b * NK * NC + tid * NC);
                mo4[0] = a; mo4[1] = q; mo4[2] = r; mo4[3] = s;
            }
        }
    } else {
        float* gnumR = ws + GNUM_OFF + (size_t)finR * NB * NK * NC + (size_t)b * NK * NC;
        float* gdenR = ws + GDEN_OFF + finR * NB * NK + b * NK;
        if (tid < NK) {
            const int k = tid;
            float den = gdenR[k];
            const float4* gn4 = reinterpret_cast<const float4*>(gnumR + k * NC);
            const float4* mp4 = reinterpret_cast<const float4*>(mPrev + k * NC);
            float4 g0 = gn4[0], g1 = gn4[1], g2 = gn4[2], g3 = gn4[3];
            float4 o0 = mp4[0], o1 = mp4[1], o2 = mp4[2], o3 = mp4[3];
            float gg[NC] = {g0.x,g0.y,g0.z,g0.w, g1.x,g1.y,g1.z,g1.w,
                            g2.x,g2.y,g2.z,g2.w, g3.x,g3.y,g3.z,g3.w};
            float oo[NC] = {o0.x,o0.y,o0.z,o0.w, o1.x,o1.y,o1.z,o1.w,
                            o2.x,o2.y,o2.z,o2.w, o3.x,o3.y,o3.z,o3.w};
            float inv = fmaxf(den, 1.f);
            bool pos = den > 0.f;
            float nm[NC];
            #pragma unroll
            for (int c = 0; c < NC; ++c) nm[c] = pos ? (gg[c] / inv) : oo[c];
            #pragma unroll
            for (int c = 0; c < NC; ++c) sm[k][c] = nm[c];
            float s = 0.f;
            #pragma unroll
            for (int c = 0; c < NC; ++c) s += nm[c] * nm[c];
            sm2[k] = s;
            if (tile == 0) {
                float* mo = out + (size_t)NB * NP + (size_t)b * NK * NC + k * NC;
                float4* mo4 = reinterpret_cast<float4*>(mo);
                mo4[0] = make_float4(nm[0], nm[1], nm[2], nm[3]);
                mo4[1] = make_float4(nm[4], nm[5], nm[6], nm[7]);
                mo4[2] = make_float4(nm[8], nm[9], nm[10], nm[11]);
                mo4[3] = make_float4(nm[12], nm[13], nm[14], nm[15]);
            }
        }
    }

    // ---- 2 points per thread (coalesced, strided by TPB), unroll-2 over k ----
    const int pA = tile * LTILEP + tid;
    const int pB = pA + TPB;
    float frA[NC], frB[NC];
    #pragma unroll
    for (int c = 0; c < NC; ++c) {
        const float* row = feat + ((size_t)b * NC + c) * NP;
        frA[c] = row[pA];
        frB[c] = row[pB];
    }
    float f2A = 0.f, f2B = 0.f;
    #pragma unroll
    for (int c = 0; c < NC; ++c) f2A += frA[c] * frA[c];
    #pragma unroll
    for (int c = 0; c < NC; ++c) f2B += frB[c] * frB[c];
    __syncthreads();

    float bestA = 3.4e38f, bestB = 3.4e38f;
    int biA = 0, biB = 0;
    const float4* smv = reinterpret_cast<const float4*>(&sm[0][0]);
    #pragma unroll 2
    for (int k = 0; k < NK; ++k) {
        float4 m0 = smv[k * 4 + 0], m1 = smv[k * 4 + 1];
        float4 m2v = smv[k * 4 + 2], m3 = smv[k * 4 + 3];
        float mm[NC] = {m0.x,m0.y,m0.z,m0.w, m1.x,m1.y,m1.z,m1.w,
                        m2v.x,m2v.y,m2v.z,m2v.w, m3.x,m3.y,m3.z,m3.w};
        float m2 = sm2[k];
        float dA = 0.f, dB = 0.f;
        #pragma unroll
        for (int c = 0; c < NC; ++c) {
            float mc = mm[c];
            dA = fmaf(frA[c], mc, dA);
            dB = fmaf(frB[c], mc, dB);
        }
        float d2A = (f2A - 2.f * dA) + m2;
        float d2B = (f2B - 2.f * dB) + m2;
        if (d2A < bestA) { bestA = d2A; biA = k; }
        if (d2B < bestB) { bestB = d2B; biB = k; }
    }

    out[(size_t)b * NP + pA] = (bestA < BW2) ? (float)(biA + 1) : 0.f;
    out[(size_t)b * NP + pB] = (bestB < BW2) ? (float)(biB + 1) : 0.f;
}

extern "C" void kernel_launch(void* const* d_in, const int* in_sizes, int n_in,
                              void* d_out, int out_size, void* d_ws, size_t ws_size,
                              hipStream_t stream) {
    const float* feat = (const float*)d_in[0];
    const int* seed = (const int*)d_in[1];
    float* out = (float*)d_out;
    float* ws = (float*)d_ws;

    ms_init<<<84, 256, 0, stream>>>(feat, seed, ws);
    for (int i = 0; i < NITER; ++i) {
        ms_accum<<<NB * NTILES * KS, TPB, 0, stream>>>(
            feat, ws, (i + 2) % 3, i % 3, (i + 1) % 3, (i + 1) & 1, i & 1, i);
    }
    ms_label<<<NB * LNT, TPB, 0, stream>>>(feat, ws, out);
}